// Round 12
// baseline (292.309 us; speedup 1.0000x reference)
//
#include <hip/hip_runtime.h>
#include <stdint.h>
#include <math.h>

// EncoderBlock: x:(2,2048,1024) f32. All GEMMs in bf16 MFMA.
// R12: buffer-parity unrolling (#pragma unroll 2) on all double-buffered
//      loops (flash_attn t-loop, gemm256/gemm_bt K-loops) so the buffer index
//      is compile-time -> swizzled LDS addresses hoisted out of the loop.

#define DM   1024
#define DFF  4096
#define NH   16
#define DKH  64
#define TSEQ 2048
#define TOK  4096   // 2*2048 tokens

using f32x4  = float  __attribute__((ext_vector_type(4)));
using bf16x8 = __bf16 __attribute__((ext_vector_type(8)));
using s16x8  = short  __attribute__((ext_vector_type(8)));

typedef const void __attribute__((address_space(1)))* gas_ptr;
typedef void       __attribute__((address_space(3)))* las_ptr;

__device__ __forceinline__ short f2bf(float f) {
  unsigned u; __builtin_memcpy(&u, &f, 4);
  u += 0x7FFFu + ((u >> 16) & 1u);      // RNE (inputs finite)
  return (short)(u >> 16);
}
__device__ __forceinline__ float bf2f(short s) {
  unsigned u = ((unsigned)(unsigned short)s) << 16;
  float f; __builtin_memcpy(&f, &u, 4);
  return f;
}
__device__ __forceinline__ unsigned cvt_pk_bf16(float lo, float hi) {
  unsigned r;
  asm volatile("v_cvt_pk_bf16_f32 %0, %1, %2" : "=v"(r) : "v"(lo), "v"(hi));
  return r;
}
__device__ __forceinline__ f32x4 mfma16(s16x8 a, s16x8 b, f32x4 c) {
  return __builtin_amdgcn_mfma_f32_16x16x32_bf16(
      __builtin_bit_cast(bf16x8, a), __builtin_bit_cast(bf16x8, b), c, 0, 0, 0);
}
__device__ __forceinline__ void gload16(const void* g, void* l) {
  __builtin_amdgcn_global_load_lds((gas_ptr)g, (las_ptr)l, 16, 0, 0);
}
// tanh-form GELU via exp2 (max |err| ~3e-4 vs exact)
__device__ __forceinline__ float gelu_f(float x) {
  float u = x * (0.7978845608f + 0.0356774081f * x * x);
  float e = exp2f(u * 2.8853900818f);
  return x - x / (1.f + e);
}

// ---------------------------------------------------------------- conversions
struct CvtArgs { const float* S[4]; short* D[4]; long n[4]; };
__global__ void cvt_bf16_b(CvtArgs a) {
  const int z = blockIdx.y;
  long i = ((long)blockIdx.x * 256 + threadIdx.x) * 8;
  if (i >= a.n[z]) return;
  const float* S = a.S[z]; short* D = a.D[z];
  float4 va = *(const float4*)(S + i);
  float4 vb = *(const float4*)(S + i + 4);
  s16x8 o;
  o[0]=f2bf(va.x); o[1]=f2bf(va.y); o[2]=f2bf(va.z); o[3]=f2bf(va.w);
  o[4]=f2bf(vb.x); o[5]=f2bf(vb.y); o[6]=f2bf(vb.z); o[7]=f2bf(vb.w);
  *(s16x8*)(D + i) = o;
}

// W: R x C f32 (row-major)  ->  WT: C x R bf16 (row-major). Batched over z.
struct TcvtArgs { const float* W[4]; short* WT[4]; };
template<int NZ>
__global__ __launch_bounds__(256) void transpose_cvt(TcvtArgs a, int R, int C) {
  __shared__ float t[64][65];
  const int z = (NZ > 1) ? blockIdx.z : 0;
  const float* __restrict__ W = a.W[z];
  short* __restrict__ WT = a.WT[z];
  const int c0 = blockIdx.x * 64, r0 = blockIdx.y * 64;
  const int tr = threadIdx.x >> 4, tc = (threadIdx.x & 15) * 4;
  #pragma unroll
  for (int q = 0; q < 4; q++) {
    int rr = q * 16 + tr;
    float4 v = *(const float4*)(W + (long)(r0 + rr) * C + c0 + tc);
    t[rr][tc] = v.x; t[rr][tc+1] = v.y; t[rr][tc+2] = v.z; t[rr][tc+3] = v.w;
  }
  __syncthreads();
  #pragma unroll
  for (int q = 0; q < 4; q++) {
    int rr = q * 16 + tr;
    short4 o;
    o.x = f2bf(t[tc+0][rr]); o.y = f2bf(t[tc+1][rr]);
    o.z = f2bf(t[tc+2][rr]); o.w = f2bf(t[tc+3][rr]);
    *(short4*)(WT + (long)(c0 + rr) * R + r0 + tc) = o;
  }
}

// bc[n] = sum_k be[k] * W[k][n] + b2[n],  W given as WT (N x K bf16)
struct BiasArgs {
  const float* be[3]; const short* WT[3]; const float* b2[3]; float* bc[3]; int K;
};
__global__ void fuse_bias(BiasArgs a) {
  const int z = blockIdx.y, n = blockIdx.x, lane = threadIdx.x;
  const float* be = a.be[z];
  const short* WT = a.WT[z] + (long)n * a.K;
  float s = 0.f;
  for (int k = lane; k < a.K; k += 64) s += be[k] * bf2f(WT[k]);
  #pragma unroll
  for (int d = 1; d < 64; d <<= 1) s += __shfl_xor(s, d);
  if (lane == 0) a.bc[z][n] = s + a.b2[z][n];
}

// ------------------------------------------------------------------- GEMM_BT (128^2)
// Stage-ahead LDS double-buffer, one barrier per K-step; K-loop unrolled x2
// so the buffer index is compile-time (addresses hoisted).
struct GemmArgs {
  const short* A[3]; const short* B[3]; const float* bias[3]; void* C[6];
  float oscale[3];
  int M, N, K;
  int tmask;   // bit prob: write C transposed (bf16 only), ld = M
  int zshift;  // log2(splitk)
};

template<int EPI>   // 0: bf16 out, 1: f32 out, 2: bf16 out + GELU
__global__ __launch_bounds__(256) void gemm_bt(GemmArgs g) {
  const int zz = blockIdx.z;
  const int prob = zz >> g.zshift;
  const int slice = zz & ((1 << g.zshift) - 1);
  const short* __restrict__ A = g.A[prob];
  const short* __restrict__ B = g.B[prob];
  const float* __restrict__ bias = g.bias[prob];
  const int N = g.N, K = g.K;
  const int Ks = K >> g.zshift;
  const int kbase = slice * Ks;
  const int tn = blockIdx.x * 128, tm = blockIdx.y * 128;
  const int tid = threadIdx.x;
  const int lane = tid & 63, w = tid >> 6;
  const int wr = w >> 1, wc = w & 1;
  const int g2 = lane >> 4, q = lane & 15;

  // lbuf[0..1] = A double-buffer, lbuf[2..3] = B double-buffer (64KB total)
  __shared__ alignas(16) short lbuf[4][128 * 64];

  f32x4 acc[4][4] = {};

  const int srow = lane >> 3;
  const int scol = lane & 7;

  auto STAGE = [&](int k0, int bf) {
    #pragma unroll
    for (int qq = 0; qq < 4; qq++) {
      const int row  = w * 32 + qq * 8 + srow;
      const int slot = scol ^ (row & 7);
      gload16(A + (long)(tm + row) * K + kbase + k0 + slot * 8,
              &lbuf[bf][(w * 32 + qq * 8) * 64]);
      gload16(B + (long)(tn + row) * K + kbase + k0 + slot * 8,
              &lbuf[2 + bf][(w * 32 + qq * 8) * 64]);
    }
  };

  STAGE(0, 0);
  __syncthreads();                       // drain prologue stage

  const int nk = Ks >> 6;
  #pragma unroll 2
  for (int it = 0; it < nk; it++) {
    const int cur = it & 1;
    if (it + 1 < nk) STAGE((it + 1) << 6, cur ^ 1);   // fly under compute

    const short* cA = &lbuf[cur][0];
    const short* cB = &lbuf[2 + cur][0];
    #pragma unroll
    for (int kk = 0; kk < 2; kk++) {
      s16x8 af[4], bfr[4];
      #pragma unroll
      for (int m = 0; m < 4; m++) {
        const int row = wr * 64 + m * 16 + q;
        const int ps  = (kk * 4 + g2) ^ (row & 7);
        af[m] = *(const s16x8*)(cA + row * 64 + ps * 8);
      }
      #pragma unroll
      for (int n = 0; n < 4; n++) {
        const int row = wc * 64 + n * 16 + q;
        const int ps  = (kk * 4 + g2) ^ (row & 7);
        bfr[n] = *(const s16x8*)(cB + row * 64 + ps * 8);
      }
      __builtin_amdgcn_s_setprio(1);
      #pragma unroll
      for (int m = 0; m < 4; m++)
        #pragma unroll
        for (int n = 0; n < 4; n++)
          acc[m][n] = mfma16(af[m], bfr[n], acc[m][n]);
      __builtin_amdgcn_s_setprio(0);
    }
    __syncthreads();                     // drains stage(it+1) (covered by compute)
  }

  const bool outT = (g.tmask >> prob) & 1;
  const float sc = g.oscale[prob];
  float bv[4];
  #pragma unroll
  for (int n = 0; n < 4; n++)
    bv[n] = bias ? bias[tn + wc * 64 + n * 16 + q] : 0.f;

  if (EPI == 1) {
    float* C = (float*)g.C[zz];
    #pragma unroll
    for (int n = 0; n < 4; n++) {
      const int col = tn + wc * 64 + n * 16 + q;
      #pragma unroll
      for (int m = 0; m < 4; m++) {
        const int row0 = tm + wr * 64 + m * 16 + g2 * 4;
        #pragma unroll
        for (int r = 0; r < 4; r++)
          C[(long)(row0 + r) * N + col] = (acc[m][n][r] + bv[n]) * sc;
      }
    }
  } else {
    short* lC = &lbuf[0][0];             // 8704 shorts needed, 32768 available
    short* C = (short*)g.C[zz];
    #pragma unroll
    for (int h2 = 0; h2 < 2; h2++) {
      __syncthreads();
      if (!outT ? (wr == h2) : (wc == h2)) {
        #pragma unroll
        for (int m = 0; m < 4; m++)
          #pragma unroll
          for (int n = 0; n < 4; n++)
            #pragma unroll
            for (int r = 0; r < 4; r++) {
              float xv = (acc[m][n][r] + bv[n]) * sc;
              if (EPI == 2) xv = gelu_f(xv);
              if (!outT) {
                const int rl = m * 16 + g2 * 4 + r;
                const int cl = wc * 64 + n * 16 + q;
                lC[rl * 136 + cl] = f2bf(xv);
              } else {
                const int cl = n * 16 + q;
                const int rl = wr * 64 + m * 16 + g2 * 4 + r;
                lC[cl * 136 + rl] = f2bf(xv);
              }
            }
      }
      __syncthreads();
      const int lrow = tid >> 4, l16 = tid & 15;
      #pragma unroll
      for (int rr = 0; rr < 4; rr++) {
        const int row = rr * 16 + lrow;
        s16x8 vv = *(const s16x8*)(lC + row * 136 + l16 * 8);
        if (!outT)
          *(s16x8*)(C + (long)(tm + h2 * 64 + row) * N + tn + l16 * 8) = vv;
        else
          *(s16x8*)(C + (long)(tn + h2 * 64 + row) * g.M + tm + l16 * 8) = vv;
      }
    }
  }
}

// ------------------------------------------------------------------- GEMM256
struct Gemm256Args {
  const short* A[3]; const short* B[3]; const float* bias[3]; void* C[3];
  float oscale[3];
  int M, N, K;
  int tmask;
};

template<int EPI>   // 0: bf16, 2: bf16 + GELU
__global__ __launch_bounds__(512, 2) void gemm256(Gemm256Args g) {
  const int prob = blockIdx.z;
  const short* __restrict__ A = g.A[prob];
  const short* __restrict__ B = g.B[prob];
  const float* __restrict__ bias = g.bias[prob];
  const int N = g.N, K = g.K;

  const int gx = gridDim.x;
  const int nwg = gx * gridDim.y;
  const int bid = blockIdx.y * gx + blockIdx.x;
  const int cpx = nwg >> 3;
  const int tile = (bid & 7) * cpx + (bid >> 3);
  const int tn = (tile % gx) * 256, tm = (tile / gx) * 256;

  const int tid = threadIdx.x;
  const int lane = tid & 63, w = tid >> 6;     // 8 waves
  const int wr = w >> 2, wc = w & 3;           // 2 x 4
  const int g2 = lane >> 4, q = lane & 15;
  const int srow = lane >> 3, scol = lane & 7;

  __shared__ alignas(16) short lA[2][256 * 64];   // 64KB
  __shared__ alignas(16) short lB[2][256 * 64];   // 64KB

  f32x4 acc[8][4] = {};

  auto STAGE = [&](int kb, int bf) {
    #pragma unroll
    for (int qq = 0; qq < 4; qq++) {
      const int row  = w * 32 + qq * 8 + srow;
      const int slot = scol ^ (row & 7);
      gload16(A + (long)(tm + row) * K + kb + slot * 8, &lA[bf][(w * 32 + qq * 8) * 64]);
      gload16(B + (long)(tn + row) * K + kb + slot * 8, &lB[bf][(w * 32 + qq * 8) * 64]);
    }
  };

  STAGE(0, 0);
  __syncthreads();

  const int nk = K >> 6;
  #pragma unroll 2
  for (int it = 0; it < nk; it++) {
    const int cur = it & 1;
    if (it + 1 < nk) STAGE((it + 1) << 6, cur ^ 1);   // fly under compute

    const short* cA = &lA[cur][0];
    const short* cB = &lB[cur][0];
    s16x8 bfr[4][2];
    #pragma unroll
    for (int n = 0; n < 4; n++)
      #pragma unroll
      for (int kk = 0; kk < 2; kk++) {
        const int row = wc * 64 + n * 16 + q;
        const int ps  = (kk * 4 + g2) ^ (row & 7);
        bfr[n][kk] = *(const s16x8*)(cB + row * 64 + ps * 8);
      }
    __builtin_amdgcn_s_setprio(1);
    #pragma unroll
    for (int m = 0; m < 8; m++) {
      s16x8 af[2];
      #pragma unroll
      for (int kk = 0; kk < 2; kk++) {
        const int row = wr * 128 + m * 16 + q;
        const int ps  = (kk * 4 + g2) ^ (row & 7);
        af[kk] = *(const s16x8*)(cA + row * 64 + ps * 8);
      }
      #pragma unroll
      for (int kk = 0; kk < 2; kk++)
        #pragma unroll
        for (int n = 0; n < 4; n++)
          acc[m][n] = mfma16(af[kk], bfr[n][kk], acc[m][n]);
    }
    __builtin_amdgcn_s_setprio(0);
    __syncthreads();
  }

  // epilogue: 4 passes, fully unrolled (rule #20), coalesced via LDS bounce
  short* lC = &lA[0][0];
  short* C = (short*)g.C[prob];
  const bool outT = (g.tmask >> prob) & 1;
  const float sc = g.oscale[prob];
  float bv[4];
  #pragma unroll
  for (int n = 0; n < 4; n++)
    bv[n] = bias ? bias[tn + wc * 64 + n * 16 + q] : 0.f;

  #pragma unroll
  for (int p = 0; p < 4; p++) {
    __syncthreads();
    if (!outT) {
      if (wr == (p >> 1)) {
        const int mb = (p & 1) * 4;
        #pragma unroll
        for (int mm = 0; mm < 4; mm++)
          #pragma unroll
          for (int n = 0; n < 4; n++)
            #pragma unroll
            for (int r = 0; r < 4; r++) {
              float xv = (acc[mb + mm][n][r] + bv[n]) * sc;
              if (EPI == 2) xv = gelu_f(xv);
              lC[(mm * 16 + g2 * 4 + r) * 272 + wc * 64 + n * 16 + q] = f2bf(xv);
            }
      }
    } else {
      if (wc == p) {
        #pragma unroll
        for (int m = 0; m < 8; m++)
          #pragma unroll
          for (int n = 0; n < 4; n++)
            #pragma unroll
            for (int r = 0; r < 4; r++) {
              float xv = (acc[m][n][r] + bv[n]) * sc;
              lC[(n * 16 + q) * 272 + wr * 128 + m * 16 + g2 * 4 + r] = f2bf(xv);
            }
      }
    }
    __syncthreads();
    #pragma unroll
    for (int rr = 0; rr < 4; rr++) {
      const int row = rr * 16 + (tid >> 5);
      s16x8 vv = *(const s16x8*)(lC + row * 272 + (tid & 31) * 8);
      if (!outT)
        *(s16x8*)(C + (long)(tm + p * 64 + row) * N + tn + (tid & 31) * 8) = vv;
      else
        *(s16x8*)(C + (long)(tn + p * 64 + row) * g.M + tm + (tid & 31) * 8) = vv;
    }
  }
}

// ------------------------------------------------------------ flash attention
// R8 structure (8 waves, QBLK=128, shared K/V tiles, ones-MFMA denominator)
// + t-loop unrolled x2 so buffer parity is compile-time (addresses hoisted).
__global__ __launch_bounds__(512) void flash_attn(const short* __restrict__ Q,
                                                  const short* __restrict__ Km,
                                                  const short* __restrict__ VT,
                                                  const int* __restrict__ mask,
                                                  short* __restrict__ O) {
  const int qt = blockIdx.x;            // 0..15 (128 q-rows each)
  const int bh = blockIdx.y;
  const int b = bh >> 4, h = bh & 15;
  const int tid = threadIdx.x;
  const int lane = tid & 63, w = tid >> 6;   // 8 waves
  const int g2 = lane >> 4, q = lane & 15;

  __shared__ alignas(16) short lK[2][64 * 64];   // 16KB
  __shared__ alignas(16) short lV[2][64 * 64];   // 16KB
  __shared__ alignas(16) short lP[8][16 * 64];   // 16KB, per-wave, XOR-swizzled

  const int qrow0 = b * TSEQ + qt * 128 + w * 16;

  s16x8 qf[2];
  #pragma unroll
  for (int kk = 0; kk < 2; kk++)
    qf[kk] = *(const s16x8*)(Q + (long)(qrow0 + q) * DM + h * DKH + kk * 32 + g2 * 8);

  f32x4 oacc[4] = {};              // q' = g2*4+r, d = n*16+q
  f32x4 dacc = {};                 // denominator, q' = g2*4+r (ones-MFMA)
  s16x8 vones;
  #pragma unroll
  for (int j = 0; j < 8; j++) vones[j] = (short)0x3F80;   // bf16 1.0

  // staging: each thread stages ONE 16B chunk of K and one of V per tile.
  const int srow = lane >> 3, scol = lane & 7;
  const int strow = w * 8 + srow;             // 0..63
  const int sslot = scol ^ (strow & 7);
  short* lPw = &lP[w][0];
  const int psw = (q & 7) << 3;

  const int nt = TSEQ / 64;
  gload16(Km + (long)(b * TSEQ + strow) * DM + h * DKH + sslot * 8,
          &lK[0][(w * 8) * 64]);
  gload16(VT + (long)(h * DKH + strow) * TOK + b * TSEQ + sslot * 8,
          &lV[0][(w * 8) * 64]);

  #pragma unroll 2
  for (int t = 0; t < nt; t++) {
    const int cb = t & 1;
    const short* lKc = &lK[cb][0];
    const short* lVc = &lV[cb][0];
    __syncthreads();               // drains stage(t)

    if (t + 1 < nt) {              // stage(t+1) flies under compute
      const int kvn = (t + 1) * 64;
      gload16(Km + (long)(b * TSEQ + kvn + strow) * DM + h * DKH + sslot * 8,
              &lK[cb ^ 1][(w * 8) * 64]);
      gload16(VT + (long)(h * DKH + strow) * TOK + b * TSEQ + kvn + sslot * 8,
              &lV[cb ^ 1][(w * 8) * 64]);
    }
    const int mk = mask[b * TSEQ + t * 64 + lane];

    // QK^T (swapped): s[n][r] = score(q, kv = n*16 + g2*4 + r), log2 domain
    f32x4 s[4] = {};
    __builtin_amdgcn_s_setprio(1);
    #pragma unroll
    for (int kk = 0; kk < 2; kk++)
      #pragma unroll
      for (int n = 0; n < 4; n++) {
        const int row = n * 16 + q;
        const int ps  = (kk * 4 + g2) ^ (row & 7);
        s16x8 kf = *(const s16x8*)(lKc + row * 64 + ps * 8);
        s[n] = mfma16(kf, qf[kk], s[n]);
      }
    __builtin_amdgcn_s_setprio(0);

    float p[4][4];
    #pragma unroll
    for (int n = 0; n < 4; n++)
      #pragma unroll
      for (int r = 0; r < 4; r++)
        p[n][r] = exp2f(s[n][r]);

    // mask slow path (fast path: mask all ones -> skipped)
    if (__ballot(mk == 0)) {
      const float mzf = mk ? 1.f : 0.f;
      #pragma unroll
      for (int n = 0; n < 4; n++)
        #pragma unroll
        for (int r = 0; r < 4; r++)
          p[n][r] *= __shfl(mzf, n * 16 + g2 * 4 + r);
    }

    // pack P pairs -> per-wave LDS (b32, swizzled); no barrier needed
    #pragma unroll
    for (int n = 0; n < 4; n++)
      #pragma unroll
      for (int hh = 0; hh < 2; hh++) {
        unsigned pk = cvt_pk_bf16(p[n][2 * hh], p[n][2 * hh + 1]);
        *(unsigned*)(lPw + ((q * 64 + n * 16 + g2 * 4 + 2 * hh) ^ psw)) = pk;
      }
    s16x8 pf[2];
    #pragma unroll
    for (int kk = 0; kk < 2; kk++)
      pf[kk] = *(const s16x8*)(lPw + ((q * 64 + kk * 32 + g2 * 8) ^ psw));

    // PV + denominator: oacc[n] += P x V^T ; dacc += P x ones
    __builtin_amdgcn_s_setprio(1);
    #pragma unroll
    for (int kk = 0; kk < 2; kk++) {
      #pragma unroll
      for (int n = 0; n < 4; n++) {
        const int row = n * 16 + q;
        const int ps  = (kk * 4 + g2) ^ (row & 7);
        s16x8 vf = *(const s16x8*)(lVc + row * 64 + ps * 8);
        oacc[n] = mfma16(pf[kk], vf, oacc[n]);
      }
      dacc = mfma16(pf[kk], vones, dacc);
    }
    __builtin_amdgcn_s_setprio(0);
  }

  float rI[4];
  #pragma unroll
  for (int r = 0; r < 4; r++) rI[r] = 1.f / dacc[r];
  #pragma unroll
  for (int n = 0; n < 4; n++) {
    const int col = h * DKH + n * 16 + q;
    #pragma unroll
    for (int r = 0; r < 4; r++) {
      const int row = qrow0 + g2 * 4 + r;
      O[(long)row * DM + col] = f2bf(oacc[n][r] * rI[r]);
    }
  }
}

// ---------------------------------------------- residual (2 partials) + LN
template<bool WB16>
__global__ __launch_bounds__(256) void ln_residual(const float* __restrict__ X,
                                                   const float* __restrict__ P0,
                                                   const float* __restrict__ P1,
                                                   const float* __restrict__ rbias,
                                                   const float* __restrict__ gw,
                                                   const float* __restrict__ bw,
                                                   float* __restrict__ Yf,
                                                   short* __restrict__ Yb) {
  const int row = blockIdx.x, tid = threadIdx.x;
  const float4 xv = *(const float4*)(X + (long)row * DM + tid * 4);
  const float4 p0 = *(const float4*)(P0 + (long)row * DM + tid * 4);
  const float4 p1 = *(const float4*)(P1 + (long)row * DM + tid * 4);
  const float4 rb = *(const float4*)(rbias + tid * 4);
  float v[4] = {xv.x + p0.x + p1.x + rb.x, xv.y + p0.y + p1.y + rb.y,
                xv.z + p0.z + p1.z + rb.z, xv.w + p0.w + p1.w + rb.w};
  float s  = v[0] + v[1] + v[2] + v[3];
  float s2 = v[0]*v[0] + v[1]*v[1] + v[2]*v[2] + v[3]*v[3];
  #pragma unroll
  for (int d = 1; d < 64; d <<= 1) { s += __shfl_xor(s, d); s2 += __shfl_xor(s2, d); }
  __shared__ float red[8];
  const int lane = tid & 63, w = tid >> 6;
  if (lane == 0) { red[w] = s; red[w + 4] = s2; }
  __syncthreads();
  s  = red[0] + red[1] + red[2] + red[3];
  s2 = red[4] + red[5] + red[6] + red[7];
  const float mu  = s * (1.f / DM);
  const float inv = rsqrtf(s2 * (1.f / DM) - mu * mu + 1e-5f);
  #pragma unroll
  for (int i = 0; i < 4; i++) {
    const int col = tid * 4 + i;
    const float y = (v[i] - mu) * inv * gw[col] + bw[col];
    Yf[(long)row * DM + col] = y;
    if (WB16) Yb[(long)row * DM + col] = f2bf(y);
  }
}

// ------------------------------------------------------------------ launcher
extern "C" void kernel_launch(void* const* d_in, const int* in_sizes, int n_in,
                              void* d_out, int out_size, void* d_ws, size_t ws_size,
                              hipStream_t stream) {
  const float* x   = (const float*)d_in[0];
  const int*   msk = (const int*)d_in[1];
  const float* Wqe = (const float*)d_in[2];  const float* bqe = (const float*)d_in[3];
  const float* Wke = (const float*)d_in[4];  const float* bke = (const float*)d_in[5];
  const float* Wve = (const float*)d_in[6];  const float* bve = (const float*)d_in[7];
  const float* Wq  = (const float*)d_in[8];  const float* bq  = (const float*)d_in[9];
  const float* Wk  = (const float*)d_in[10]; const float* bk  = (const float*)d_in[11];
  const float* Wv  = (const float*)d_in[12]; const float* bv  = (const float*)d_in[13];
  const float* Wo  = (const float*)d_in[14]; const float* bo  = (const float*)d_in[15];
  const float* g1  = (const float*)d_in[16]; const float* b1  = (const float*)d_in[17];
  const float* g2  = (const float*)d_in[18]; const float* b2  = (const float*)d_in[19];
  const float* W1  = (const float*)d_in[20]; const float* bb1 = (const float*)d_in[21];
  const float* W2  = (const float*)d_in[22]; const float* bb2 = (const float*)d_in[23];

  char* ws = (char*)d_ws;
  const size_t MB = 1024ull * 1024ull;
  short* xb   = (short*)(ws + 0);          // 8MB; reused as attention output
  short* woT  = (short*)(ws + 8 * MB);     // 2MB
  short* w1T  = (short*)(ws + 10 * MB);    // 8MB
  short* w2T  = (short*)(ws + 18 * MB);    // 8MB
  short* wqeB = (short*)(ws + 26 * MB);    // 2MB each (dead after fusion gemm)
  short* wkeB = (short*)(ws + 28 * MB);
  short* wveB = (short*)(ws + 30 * MB);
  short* wqT  = (short*)(ws + 32 * MB);
  short* wkT  = (short*)(ws + 34 * MB);
  short* wvT  = (short*)(ws + 36 * MB);
  short* wcqT = (short*)(ws + 38 * MB);    // fused weights (dead after QKV)
  short* wckT = (short*)(ws + 40 * MB);
  short* wcvT = (short*)(ws + 42 * MB);
  float* bcq  = (float*)(ws + 44 * MB);
  float* bck  = (float*)(ws + 44 * MB + 16384);
  float* bcv  = (float*)(ws + 44 * MB + 32768);
  short* Qb   = (short*)(ws + 45 * MB);    // 8MB (dead after attention)
  short* Kb2  = (short*)(ws + 53 * MB);    // 8MB
  short* VTb  = (short*)(ws + 61 * MB);    // 8MB (dead after attention)
  float* mhaP0= (float*)(ws + 26 * MB);    // 16MB [Wo .. LN1]
  float* mhaP1= (float*)(ws + 42 * MB);    // 16MB
  short* Hb   = (short*)(ws + 26 * MB);    // 32MB [FFN1 .. FFN2]
  float* yf   = (float*)(ws + 58 * MB);    // 16MB
  short* ybf  = (short*)(ws + 74 * MB);    // 8MB (dead after FFN1)
  float* ffnP0= (float*)d_out;             // 16MB [FFN2 .. LN2]
  float* ffnP1= (float*)(ws + 0);          // 16MB (xb/woT/w1T dead by FFN2)
  short* Aout = xb;

  // 1. conversions
  CvtArgs ca = {};
  ca.S[0] = x;  ca.D[0] = xb;   ca.n[0] = (long)TOK * DM;
  ca.S[1] = Wqe; ca.D[1] = wqeB; ca.n[1] = (long)DM * DM;
  ca.S[2] = Wke; ca.D[2] = wkeB; ca.n[2] = (long)DM * DM;
  ca.S[3] = Wve; ca.D[3] = wveB; ca.n[3] = (long)DM * DM;
  cvt_bf16_b<<<dim3((long)TOK * DM / 2048, 4), 256, 0, stream>>>(ca);

  TcvtArgs t4 = {};
  t4.W[0] = Wq; t4.WT[0] = wqT;  t4.W[1] = Wk; t4.WT[1] = wkT;
  t4.W[2] = Wv; t4.WT[2] = wvT;  t4.W[3] = Wo; t4.WT[3] = woT;
  transpose_cvt<4><<<dim3(16, 16, 4), 256, 0, stream>>>(t4, DM, DM);
  TcvtArgs t1 = {}; t1.W[0] = W1; t1.WT[0] = w1T;
  transpose_cvt<1><<<dim3(64, 16), 256, 0, stream>>>(t1, DM, DFF);
  TcvtArgs t2 = {}; t2.W[0] = W2; t2.WT[0] = w2T;
  transpose_cvt<1><<<dim3(16, 64), 256, 0, stream>>>(t2, DFF, DM);

  // 2. fused weights: WcT_z = Wz^T @ Wze^T, bf16 (128^2 kernel)
  GemmArgs fa = {};
  fa.A[0] = wqT;  fa.A[1] = wkT;  fa.A[2] = wvT;
  fa.B[0] = wqeB; fa.B[1] = wkeB; fa.B[2] = wveB;
  fa.C[0] = wcqT; fa.C[1] = wckT; fa.C[2] = wcvT;
  fa.oscale[0] = 1.f; fa.oscale[1] = 1.f; fa.oscale[2] = 1.f;
  fa.M = DM; fa.N = DM; fa.K = DM; fa.tmask = 0; fa.zshift = 0;
  gemm_bt<0><<<dim3(8, 8, 3), 256, 0, stream>>>(fa);

  // 3. fused biases
  BiasArgs ba = {};
  ba.be[0] = bqe; ba.be[1] = bke; ba.be[2] = bve;
  ba.WT[0] = wqT; ba.WT[1] = wkT; ba.WT[2] = wvT;
  ba.b2[0] = bq;  ba.b2[1] = bk;  ba.b2[2] = bv;
  ba.bc[0] = bcq; ba.bc[1] = bck; ba.bc[2] = bcv; ba.K = DM;
  fuse_bias<<<dim3(DM, 3), 64, 0, stream>>>(ba);

  // 4. Q,K,V = xb @ Wc + bc (gemm256; V transposed; Q in exp2 domain)
  Gemm256Args qa = {};
  qa.A[0] = xb;   qa.A[1] = xb;   qa.A[2] = xb;
  qa.B[0] = wcqT; qa.B[1] = wckT; qa.B[2] = wcvT;
  qa.bias[0] = bcq; qa.bias[1] = bck; qa.bias[2] = bcv;
  qa.C[0] = Qb; qa.C[1] = Kb2; qa.C[2] = VTb;
  qa.oscale[0] = 0.125f * 1.44269504f; qa.oscale[1] = 1.f; qa.oscale[2] = 1.f;
  qa.M = TOK; qa.N = DM; qa.K = DM; qa.tmask = 4;
  gemm256<0><<<dim3(4, 16, 3), 512, 0, stream>>>(qa);

  // 5. attention (8-wave, QBLK=128)
  flash_attn<<<dim3(TSEQ / 128, 2 * NH), 512, 0, stream>>>(Qb, Kb2, VTb, msk, Aout);

  // 6. mha partials = Aout @ Wo (128^2 split-K x2, f32)
  GemmArgs oa = {};
  oa.A[0] = Aout; oa.B[0] = woT; oa.bias[0] = nullptr;
  oa.C[0] = mhaP0; oa.C[1] = mhaP1;
  oa.oscale[0] = 1.f;
  oa.M = TOK; oa.N = DM; oa.K = DM; oa.tmask = 0; oa.zshift = 1;
  gemm_bt<1><<<dim3(8, 32, 2), 256, 0, stream>>>(oa);

  // 7. y = LN(x + mhaP0 + mhaP1 + bo)
  ln_residual<true><<<dim3(TOK), 256, 0, stream>>>(x, mhaP0, mhaP1, bo,
                                                   g1, b1, yf, ybf);

  // 8. H = gelu(y @ W1 + bb1)  (gemm256)
  Gemm256Args f1 = {};
  f1.A[0] = ybf; f1.B[0] = w1T; f1.bias[0] = bb1; f1.C[0] = Hb;
  f1.oscale[0] = 1.f;
  f1.M = TOK; f1.N = DFF; f1.K = DM; f1.tmask = 0;
  gemm256<2><<<dim3(16, 16, 1), 512, 0, stream>>>(f1);

  // 9. ffn partials = H @ W2 (128^2 split-K x2, f32)
  GemmArgs f2 = {};
  f2.A[0] = Hb; f2.B[0] = w2T; f2.bias[0] = nullptr;
  f2.C[0] = ffnP0; f2.C[1] = ffnP1;
  f2.oscale[0] = 1.f;
  f2.M = TOK; f2.N = DM; f2.K = DFF; f2.tmask = 0; f2.zshift = 1;
  gemm_bt<1><<<dim3(8, 32, 2), 256, 0, stream>>>(f2);

  // 10. out = LN(yf + ffnP0 + ffnP1 + bb2)
  ln_residual<false><<<dim3(TOK), 256, 0, stream>>>(yf, ffnP0, ffnP1, bb2,
                                                    g2, b2, (float*)d_out, nullptr);
}

// Round 13
// 287.169 us; speedup vs baseline: 1.0179x; 1.0179x over previous
//
#include <hip/hip_runtime.h>
#include <stdint.h>
#include <math.h>

// EncoderBlock: x:(2,2048,1024) f32. All GEMMs in bf16 MFMA.
// R13: flash_attn KVBLK=128 (halved barriers/loop overhead, PV in two kv-halves
//      sharing the per-wave lP buffer); 3 transpose dispatches merged into 1.

#define DM   1024
#define DFF  4096
#define NH   16
#define DKH  64
#define TSEQ 2048
#define TOK  4096   // 2*2048 tokens

using f32x4  = float  __attribute__((ext_vector_type(4)));
using bf16x8 = __bf16 __attribute__((ext_vector_type(8)));
using s16x8  = short  __attribute__((ext_vector_type(8)));

typedef const void __attribute__((address_space(1)))* gas_ptr;
typedef void       __attribute__((address_space(3)))* las_ptr;

__device__ __forceinline__ short f2bf(float f) {
  unsigned u; __builtin_memcpy(&u, &f, 4);
  u += 0x7FFFu + ((u >> 16) & 1u);      // RNE (inputs finite)
  return (short)(u >> 16);
}
__device__ __forceinline__ float bf2f(short s) {
  unsigned u = ((unsigned)(unsigned short)s) << 16;
  float f; __builtin_memcpy(&f, &u, 4);
  return f;
}
__device__ __forceinline__ unsigned cvt_pk_bf16(float lo, float hi) {
  unsigned r;
  asm volatile("v_cvt_pk_bf16_f32 %0, %1, %2" : "=v"(r) : "v"(lo), "v"(hi));
  return r;
}
__device__ __forceinline__ f32x4 mfma16(s16x8 a, s16x8 b, f32x4 c) {
  return __builtin_amdgcn_mfma_f32_16x16x32_bf16(
      __builtin_bit_cast(bf16x8, a), __builtin_bit_cast(bf16x8, b), c, 0, 0, 0);
}
__device__ __forceinline__ void gload16(const void* g, void* l) {
  __builtin_amdgcn_global_load_lds((gas_ptr)g, (las_ptr)l, 16, 0, 0);
}
// tanh-form GELU via exp2 (max |err| ~3e-4 vs exact)
__device__ __forceinline__ float gelu_f(float x) {
  float u = x * (0.7978845608f + 0.0356774081f * x * x);
  float e = exp2f(u * 2.8853900818f);
  return x - x / (1.f + e);
}

// ---------------------------------------------------------------- conversions
struct CvtArgs { const float* S[4]; short* D[4]; long n[4]; };
__global__ void cvt_bf16_b(CvtArgs a) {
  const int z = blockIdx.y;
  long i = ((long)blockIdx.x * 256 + threadIdx.x) * 8;
  if (i >= a.n[z]) return;
  const float* S = a.S[z]; short* D = a.D[z];
  float4 va = *(const float4*)(S + i);
  float4 vb = *(const float4*)(S + i + 4);
  s16x8 o;
  o[0]=f2bf(va.x); o[1]=f2bf(va.y); o[2]=f2bf(va.z); o[3]=f2bf(va.w);
  o[4]=f2bf(vb.x); o[5]=f2bf(vb.y); o[6]=f2bf(vb.z); o[7]=f2bf(vb.w);
  *(s16x8*)(D + i) = o;
}

// Merged transpose: flat grid decodes {4x 1024^2, W1 1024x4096, W2 4096x1024}.
struct Tcvt6Args { const float* W[6]; short* WT[6]; };
__global__ __launch_bounds__(256) void transpose_cvt6(Tcvt6Args a) {
  __shared__ float t[64][65];
  const int bid = blockIdx.x;
  int z, bx, by, R, C;
  if (bid < 1024)      { z = bid >> 8; int u = bid & 255;  bx = u & 15; by = u >> 4; R = 1024; C = 1024; }
  else if (bid < 2048) { z = 4;        int u = bid - 1024; bx = u & 63; by = u >> 6; R = 1024; C = 4096; }
  else                 { z = 5;        int u = bid - 2048; bx = u & 15; by = u >> 4; R = 4096; C = 1024; }
  const float* __restrict__ W = a.W[z];
  short* __restrict__ WT = a.WT[z];
  const int c0 = bx * 64, r0 = by * 64;
  const int tr = threadIdx.x >> 4, tc = (threadIdx.x & 15) * 4;
  #pragma unroll
  for (int q = 0; q < 4; q++) {
    int rr = q * 16 + tr;
    float4 v = *(const float4*)(W + (long)(r0 + rr) * C + c0 + tc);
    t[rr][tc] = v.x; t[rr][tc+1] = v.y; t[rr][tc+2] = v.z; t[rr][tc+3] = v.w;
  }
  __syncthreads();
  #pragma unroll
  for (int q = 0; q < 4; q++) {
    int rr = q * 16 + tr;
    short4 o;
    o.x = f2bf(t[tc+0][rr]); o.y = f2bf(t[tc+1][rr]);
    o.z = f2bf(t[tc+2][rr]); o.w = f2bf(t[tc+3][rr]);
    *(short4*)(WT + (long)(c0 + rr) * R + r0 + tc) = o;
  }
}

// bc[n] = sum_k be[k] * W[k][n] + b2[n],  W given as WT (N x K bf16)
struct BiasArgs {
  const float* be[3]; const short* WT[3]; const float* b2[3]; float* bc[3]; int K;
};
__global__ void fuse_bias(BiasArgs a) {
  const int z = blockIdx.y, n = blockIdx.x, lane = threadIdx.x;
  const float* be = a.be[z];
  const short* WT = a.WT[z] + (long)n * a.K;
  float s = 0.f;
  for (int k = lane; k < a.K; k += 64) s += be[k] * bf2f(WT[k]);
  #pragma unroll
  for (int d = 1; d < 64; d <<= 1) s += __shfl_xor(s, d);
  if (lane == 0) a.bc[z][n] = s + a.b2[z][n];
}

// ------------------------------------------------------------------- GEMM_BT (128^2)
struct GemmArgs {
  const short* A[3]; const short* B[3]; const float* bias[3]; void* C[6];
  float oscale[3];
  int M, N, K;
  int tmask;   // bit prob: write C transposed (bf16 only), ld = M
  int zshift;  // log2(splitk)
};

template<int EPI>   // 0: bf16 out, 1: f32 out, 2: bf16 out + GELU
__global__ __launch_bounds__(256) void gemm_bt(GemmArgs g) {
  const int zz = blockIdx.z;
  const int prob = zz >> g.zshift;
  const int slice = zz & ((1 << g.zshift) - 1);
  const short* __restrict__ A = g.A[prob];
  const short* __restrict__ B = g.B[prob];
  const float* __restrict__ bias = g.bias[prob];
  const int N = g.N, K = g.K;
  const int Ks = K >> g.zshift;
  const int kbase = slice * Ks;
  const int tn = blockIdx.x * 128, tm = blockIdx.y * 128;
  const int tid = threadIdx.x;
  const int lane = tid & 63, w = tid >> 6;
  const int wr = w >> 1, wc = w & 1;
  const int g2 = lane >> 4, q = lane & 15;

  __shared__ alignas(16) short lbuf[4][128 * 64];

  f32x4 acc[4][4] = {};

  const int srow = lane >> 3;
  const int scol = lane & 7;

  auto STAGE = [&](int k0, int bf) {
    #pragma unroll
    for (int qq = 0; qq < 4; qq++) {
      const int row  = w * 32 + qq * 8 + srow;
      const int slot = scol ^ (row & 7);
      gload16(A + (long)(tm + row) * K + kbase + k0 + slot * 8,
              &lbuf[bf][(w * 32 + qq * 8) * 64]);
      gload16(B + (long)(tn + row) * K + kbase + k0 + slot * 8,
              &lbuf[2 + bf][(w * 32 + qq * 8) * 64]);
    }
  };

  STAGE(0, 0);
  __syncthreads();

  const int nk = Ks >> 6;
  #pragma unroll 2
  for (int it = 0; it < nk; it++) {
    const int cur = it & 1;
    if (it + 1 < nk) STAGE((it + 1) << 6, cur ^ 1);

    const short* cA = &lbuf[cur][0];
    const short* cB = &lbuf[2 + cur][0];
    #pragma unroll
    for (int kk = 0; kk < 2; kk++) {
      s16x8 af[4], bfr[4];
      #pragma unroll
      for (int m = 0; m < 4; m++) {
        const int row = wr * 64 + m * 16 + q;
        const int ps  = (kk * 4 + g2) ^ (row & 7);
        af[m] = *(const s16x8*)(cA + row * 64 + ps * 8);
      }
      #pragma unroll
      for (int n = 0; n < 4; n++) {
        const int row = wc * 64 + n * 16 + q;
        const int ps  = (kk * 4 + g2) ^ (row & 7);
        bfr[n] = *(const s16x8*)(cB + row * 64 + ps * 8);
      }
      __builtin_amdgcn_s_setprio(1);
      #pragma unroll
      for (int m = 0; m < 4; m++)
        #pragma unroll
        for (int n = 0; n < 4; n++)
          acc[m][n] = mfma16(af[m], bfr[n], acc[m][n]);
      __builtin_amdgcn_s_setprio(0);
    }
    __syncthreads();
  }

  const bool outT = (g.tmask >> prob) & 1;
  const float sc = g.oscale[prob];
  float bv[4];
  #pragma unroll
  for (int n = 0; n < 4; n++)
    bv[n] = bias ? bias[tn + wc * 64 + n * 16 + q] : 0.f;

  if (EPI == 1) {
    float* C = (float*)g.C[zz];
    #pragma unroll
    for (int n = 0; n < 4; n++) {
      const int col = tn + wc * 64 + n * 16 + q;
      #pragma unroll
      for (int m = 0; m < 4; m++) {
        const int row0 = tm + wr * 64 + m * 16 + g2 * 4;
        #pragma unroll
        for (int r = 0; r < 4; r++)
          C[(long)(row0 + r) * N + col] = (acc[m][n][r] + bv[n]) * sc;
      }
    }
  } else {
    short* lC = &lbuf[0][0];
    short* C = (short*)g.C[zz];
    #pragma unroll
    for (int h2 = 0; h2 < 2; h2++) {
      __syncthreads();
      if (!outT ? (wr == h2) : (wc == h2)) {
        #pragma unroll
        for (int m = 0; m < 4; m++)
          #pragma unroll
          for (int n = 0; n < 4; n++)
            #pragma unroll
            for (int r = 0; r < 4; r++) {
              float xv = (acc[m][n][r] + bv[n]) * sc;
              if (EPI == 2) xv = gelu_f(xv);
              if (!outT) {
                const int rl = m * 16 + g2 * 4 + r;
                const int cl = wc * 64 + n * 16 + q;
                lC[rl * 136 + cl] = f2bf(xv);
              } else {
                const int cl = n * 16 + q;
                const int rl = wr * 64 + m * 16 + g2 * 4 + r;
                lC[cl * 136 + rl] = f2bf(xv);
              }
            }
      }
      __syncthreads();
      const int lrow = tid >> 4, l16 = tid & 15;
      #pragma unroll
      for (int rr = 0; rr < 4; rr++) {
        const int row = rr * 16 + lrow;
        s16x8 vv = *(const s16x8*)(lC + row * 136 + l16 * 8);
        if (!outT)
          *(s16x8*)(C + (long)(tm + h2 * 64 + row) * N + tn + l16 * 8) = vv;
        else
          *(s16x8*)(C + (long)(tn + h2 * 64 + row) * g.M + tm + l16 * 8) = vv;
      }
    }
  }
}

// ------------------------------------------------------------------- GEMM256
struct Gemm256Args {
  const short* A[3]; const short* B[3]; const float* bias[3]; void* C[3];
  float oscale[3];
  int M, N, K;
  int tmask;
};

template<int EPI>   // 0: bf16, 2: bf16 + GELU
__global__ __launch_bounds__(512, 2) void gemm256(Gemm256Args g) {
  const int prob = blockIdx.z;
  const short* __restrict__ A = g.A[prob];
  const short* __restrict__ B = g.B[prob];
  const float* __restrict__ bias = g.bias[prob];
  const int N = g.N, K = g.K;

  const int gx = gridDim.x;
  const int nwg = gx * gridDim.y;
  const int bid = blockIdx.y * gx + blockIdx.x;
  const int cpx = nwg >> 3;
  const int tile = (bid & 7) * cpx + (bid >> 3);
  const int tn = (tile % gx) * 256, tm = (tile / gx) * 256;

  const int tid = threadIdx.x;
  const int lane = tid & 63, w = tid >> 6;     // 8 waves
  const int wr = w >> 2, wc = w & 3;           // 2 x 4
  const int g2 = lane >> 4, q = lane & 15;
  const int srow = lane >> 3, scol = lane & 7;

  __shared__ alignas(16) short lA[2][256 * 64];   // 64KB
  __shared__ alignas(16) short lB[2][256 * 64];   // 64KB

  f32x4 acc[8][4] = {};

  auto STAGE = [&](int kb, int bf) {
    #pragma unroll
    for (int qq = 0; qq < 4; qq++) {
      const int row  = w * 32 + qq * 8 + srow;
      const int slot = scol ^ (row & 7);
      gload16(A + (long)(tm + row) * K + kb + slot * 8, &lA[bf][(w * 32 + qq * 8) * 64]);
      gload16(B + (long)(tn + row) * K + kb + slot * 8, &lB[bf][(w * 32 + qq * 8) * 64]);
    }
  };

  STAGE(0, 0);
  __syncthreads();

  const int nk = K >> 6;
  #pragma unroll 2
  for (int it = 0; it < nk; it++) {
    const int cur = it & 1;
    if (it + 1 < nk) STAGE((it + 1) << 6, cur ^ 1);

    const short* cA = &lA[cur][0];
    const short* cB = &lB[cur][0];
    s16x8 bfr[4][2];
    #pragma unroll
    for (int n = 0; n < 4; n++)
      #pragma unroll
      for (int kk = 0; kk < 2; kk++) {
        const int row = wc * 64 + n * 16 + q;
        const int ps  = (kk * 4 + g2) ^ (row & 7);
        bfr[n][kk] = *(const s16x8*)(cB + row * 64 + ps * 8);
      }
    __builtin_amdgcn_s_setprio(1);
    #pragma unroll
    for (int m = 0; m < 8; m++) {
      s16x8 af[2];
      #pragma unroll
      for (int kk = 0; kk < 2; kk++) {
        const int row = wr * 128 + m * 16 + q;
        const int ps  = (kk * 4 + g2) ^ (row & 7);
        af[kk] = *(const s16x8*)(cA + row * 64 + ps * 8);
      }
      #pragma unroll
      for (int kk = 0; kk < 2; kk++)
        #pragma unroll
        for (int n = 0; n < 4; n++)
          acc[m][n] = mfma16(af[kk], bfr[n][kk], acc[m][n]);
    }
    __builtin_amdgcn_s_setprio(0);
    __syncthreads();
  }

  // epilogue: 4 passes, fully unrolled (rule #20), coalesced via LDS bounce
  short* lC = &lA[0][0];
  short* C = (short*)g.C[prob];
  const bool outT = (g.tmask >> prob) & 1;
  const float sc = g.oscale[prob];
  float bv[4];
  #pragma unroll
  for (int n = 0; n < 4; n++)
    bv[n] = bias ? bias[tn + wc * 64 + n * 16 + q] : 0.f;

  #pragma unroll
  for (int p = 0; p < 4; p++) {
    __syncthreads();
    if (!outT) {
      if (wr == (p >> 1)) {
        const int mb = (p & 1) * 4;
        #pragma unroll
        for (int mm = 0; mm < 4; mm++)
          #pragma unroll
          for (int n = 0; n < 4; n++)
            #pragma unroll
            for (int r = 0; r < 4; r++) {
              float xv = (acc[mb + mm][n][r] + bv[n]) * sc;
              if (EPI == 2) xv = gelu_f(xv);
              lC[(mm * 16 + g2 * 4 + r) * 272 + wc * 64 + n * 16 + q] = f2bf(xv);
            }
      }
    } else {
      if (wc == p) {
        #pragma unroll
        for (int m = 0; m < 8; m++)
          #pragma unroll
          for (int n = 0; n < 4; n++)
            #pragma unroll
            for (int r = 0; r < 4; r++) {
              float xv = (acc[m][n][r] + bv[n]) * sc;
              lC[(n * 16 + q) * 272 + wr * 128 + m * 16 + g2 * 4 + r] = f2bf(xv);
            }
      }
    }
    __syncthreads();
    #pragma unroll
    for (int rr = 0; rr < 4; rr++) {
      const int row = rr * 16 + (tid >> 5);
      s16x8 vv = *(const s16x8*)(lC + row * 272 + (tid & 31) * 8);
      if (!outT)
        *(s16x8*)(C + (long)(tm + p * 64 + row) * N + tn + (tid & 31) * 8) = vv;
      else
        *(s16x8*)(C + (long)(tn + p * 64 + row) * g.M + tm + (tid & 31) * 8) = vv;
    }
  }
}

// ------------------------------------------------------------ flash attention
// v6: 8 waves, QBLK=128, KVBLK=128 (one barrier per 128 kv). K [128][64],
// V^T [64][128] (16-slot ^(row&15) swizzle). exp2 in place; PV in two kv-
// halves reusing per-wave lP. Denominator via ones-MFMA.
__global__ __launch_bounds__(512, 2) void flash_attn(const short* __restrict__ Q,
                                                     const short* __restrict__ Km,
                                                     const short* __restrict__ VT,
                                                     const int* __restrict__ mask,
                                                     short* __restrict__ O) {
  const int qt = blockIdx.x;            // 0..15 (128 q-rows each)
  const int bh = blockIdx.y;
  const int b = bh >> 4, h = bh & 15;
  const int tid = threadIdx.x;
  const int lane = tid & 63, w = tid >> 6;   // 8 waves
  const int g2 = lane >> 4, q = lane & 15;

  __shared__ alignas(16) short lK[2][128 * 64];   // 32KB
  __shared__ alignas(16) short lV[2][64 * 128];   // 32KB
  __shared__ alignas(16) short lP[8][16 * 64];    // 16KB, per-wave, swizzled

  const int qrow0 = b * TSEQ + qt * 128 + w * 16;

  s16x8 qf[2];
  #pragma unroll
  for (int kk = 0; kk < 2; kk++)
    qf[kk] = *(const s16x8*)(Q + (long)(qrow0 + q) * DM + h * DKH + kk * 32 + g2 * 8);

  f32x4 oacc[4] = {};              // q' = g2*4+r, d = n*16+q
  f32x4 dacc = {};                 // denominator (ones-MFMA)
  s16x8 vones;
  #pragma unroll
  for (int j = 0; j < 8; j++) vones[j] = (short)0x3F80;   // bf16 1.0

  // staging indices: K = two 8-row loads/wave; V = two 4-row loads/wave
  const int srow8 = lane >> 3, scol8 = lane & 7;
  const int srow16 = lane >> 4, scol16 = lane & 15;
  const int kr0 = w * 16 + srow8, kr1 = kr0 + 8;
  const int ks0 = scol8 ^ (kr0 & 7), ks1 = scol8 ^ (kr1 & 7);
  const int vr0 = w * 4 + srow16, vr1 = vr0 + 32;
  const int vs0 = scol16 ^ (vr0 & 15), vs1 = scol16 ^ (vr1 & 15);

  short* lPw = &lP[w][0];
  const int psw = (q & 7) << 3;

  auto STAGE = [&](int kvb, int bf) {
    gload16(Km + (long)(b * TSEQ + kvb + kr0) * DM + h * DKH + ks0 * 8,
            &lK[bf][(w * 16) * 64]);
    gload16(Km + (long)(b * TSEQ + kvb + kr1) * DM + h * DKH + ks1 * 8,
            &lK[bf][(w * 16 + 8) * 64]);
    gload16(VT + (long)(h * DKH + vr0) * TOK + b * TSEQ + kvb + vs0 * 8,
            &lV[bf][(w * 4) * 128]);
    gload16(VT + (long)(h * DKH + vr1) * TOK + b * TSEQ + kvb + vs1 * 8,
            &lV[bf][(32 + w * 4) * 128]);
  };

  STAGE(0, 0);

  const int nt = TSEQ / 128;   // 16
  for (int t = 0; t < nt; t++) {
    const int cb = t & 1;
    const short* lKc = &lK[cb][0];
    const short* lVc = &lV[cb][0];
    __syncthreads();               // drains stage(t)

    if (t + 1 < nt) STAGE((t + 1) * 128, cb ^ 1);
    const int mbase = b * TSEQ + t * 128;
    const int mk0 = mask[mbase + lane];
    const int mk1 = mask[mbase + 64 + lane];

    // QK^T (swapped): s[n][r] = score(q, kv = n*16 + g2*4 + r), log2 domain
    f32x4 s[8] = {};
    __builtin_amdgcn_s_setprio(1);
    #pragma unroll
    for (int kk = 0; kk < 2; kk++)
      #pragma unroll
      for (int n = 0; n < 8; n++) {
        const int row = n * 16 + q;
        const int ps  = (kk * 4 + g2) ^ (row & 7);
        s16x8 kf = *(const s16x8*)(lKc + row * 64 + ps * 8);
        s[n] = mfma16(kf, qf[kk], s[n]);
      }
    __builtin_amdgcn_s_setprio(0);

    // p = exp2(s) in place
    #pragma unroll
    for (int n = 0; n < 8; n++)
      #pragma unroll
      for (int r = 0; r < 4; r++)
        s[n][r] = exp2f(s[n][r]);

    // mask slow path (fast path: mask all ones -> skipped)
    if (__ballot(mk0 == 0) | __ballot(mk1 == 0)) {
      const float mz0 = mk0 ? 1.f : 0.f;
      const float mz1 = mk1 ? 1.f : 0.f;
      #pragma unroll
      for (int n = 0; n < 4; n++)
        #pragma unroll
        for (int r = 0; r < 4; r++) {
          s[n][r]     *= __shfl(mz0, n * 16 + g2 * 4 + r);
          s[n + 4][r] *= __shfl(mz1, n * 16 + g2 * 4 + r);
        }
    }

    // PV in two kv-halves, lP reused per half (per-wave, no barrier)
    #pragma unroll
    for (int hf = 0; hf < 2; hf++) {
      #pragma unroll
      for (int n = 0; n < 4; n++)
        #pragma unroll
        for (int hh = 0; hh < 2; hh++) {
          unsigned pk = cvt_pk_bf16(s[hf * 4 + n][2 * hh], s[hf * 4 + n][2 * hh + 1]);
          *(unsigned*)(lPw + ((q * 64 + n * 16 + g2 * 4 + 2 * hh) ^ psw)) = pk;
        }
      s16x8 pf[2];
      #pragma unroll
      for (int kk = 0; kk < 2; kk++)
        pf[kk] = *(const s16x8*)(lPw + ((q * 64 + kk * 32 + g2 * 8) ^ psw));

      __builtin_amdgcn_s_setprio(1);
      #pragma unroll
      for (int kk = 0; kk < 2; kk++) {
        #pragma unroll
        for (int n = 0; n < 4; n++) {
          const int row = n * 16 + q;                       // d-row
          const int ps  = ((hf * 2 + kk) * 4 + g2) ^ (row & 15);
          s16x8 vf = *(const s16x8*)(lVc + row * 128 + ps * 8);
          oacc[n] = mfma16(pf[kk], vf, oacc[n]);
        }
        dacc = mfma16(pf[kk], vones, dacc);
      }
      __builtin_amdgcn_s_setprio(0);
    }
  }

  float rI[4];
  #pragma unroll
  for (int r = 0; r < 4; r++) rI[r] = 1.f / dacc[r];
  #pragma unroll
  for (int n = 0; n < 4; n++) {
    const int col = h * DKH + n * 16 + q;
    #pragma unroll
    for (int r = 0; r < 4; r++) {
      const int row = qrow0 + g2 * 4 + r;
      O[(long)row * DM + col] = f2bf(oacc[n][r] * rI[r]);
    }
  }
}

// ---------------------------------------------- residual (2 partials) + LN
template<bool WB16>
__global__ __launch_bounds__(256) void ln_residual(const float* __restrict__ X,
                                                   const float* __restrict__ P0,
                                                   const float* __restrict__ P1,
                                                   const float* __restrict__ rbias,
                                                   const float* __restrict__ gw,
                                                   const float* __restrict__ bw,
                                                   float* __restrict__ Yf,
                                                   short* __restrict__ Yb) {
  const int row = blockIdx.x, tid = threadIdx.x;
  const float4 xv = *(const float4*)(X + (long)row * DM + tid * 4);
  const float4 p0 = *(const float4*)(P0 + (long)row * DM + tid * 4);
  const float4 p1 = *(const float4*)(P1 + (long)row * DM + tid * 4);
  const float4 rb = *(const float4*)(rbias + tid * 4);
  float v[4] = {xv.x + p0.x + p1.x + rb.x, xv.y + p0.y + p1.y + rb.y,
                xv.z + p0.z + p1.z + rb.z, xv.w + p0.w + p1.w + rb.w};
  float s  = v[0] + v[1] + v[2] + v[3];
  float s2 = v[0]*v[0] + v[1]*v[1] + v[2]*v[2] + v[3]*v[3];
  #pragma unroll
  for (int d = 1; d < 64; d <<= 1) { s += __shfl_xor(s, d); s2 += __shfl_xor(s2, d); }
  __shared__ float red[8];
  const int lane = tid & 63, w = tid >> 6;
  if (lane == 0) { red[w] = s; red[w + 4] = s2; }
  __syncthreads();
  s  = red[0] + red[1] + red[2] + red[3];
  s2 = red[4] + red[5] + red[6] + red[7];
  const float mu  = s * (1.f / DM);
  const float inv = rsqrtf(s2 * (1.f / DM) - mu * mu + 1e-5f);
  #pragma unroll
  for (int i = 0; i < 4; i++) {
    const int col = tid * 4 + i;
    const float y = (v[i] - mu) * inv * gw[col] + bw[col];
    Yf[(long)row * DM + col] = y;
    if (WB16) Yb[(long)row * DM + col] = f2bf(y);
  }
}

// ------------------------------------------------------------------ launcher
extern "C" void kernel_launch(void* const* d_in, const int* in_sizes, int n_in,
                              void* d_out, int out_size, void* d_ws, size_t ws_size,
                              hipStream_t stream) {
  const float* x   = (const float*)d_in[0];
  const int*   msk = (const int*)d_in[1];
  const float* Wqe = (const float*)d_in[2];  const float* bqe = (const float*)d_in[3];
  const float* Wke = (const float*)d_in[4];  const float* bke = (const float*)d_in[5];
  const float* Wve = (const float*)d_in[6];  const float* bve = (const float*)d_in[7];
  const float* Wq  = (const float*)d_in[8];  const float* bq  = (const float*)d_in[9];
  const float* Wk  = (const float*)d_in[10]; const float* bk  = (const float*)d_in[11];
  const float* Wv  = (const float*)d_in[12]; const float* bv  = (const float*)d_in[13];
  const float* Wo  = (const float*)d_in[14]; const float* bo  = (const float*)d_in[15];
  const float* g1  = (const float*)d_in[16]; const float* b1  = (const float*)d_in[17];
  const float* g2  = (const float*)d_in[18]; const float* b2  = (const float*)d_in[19];
  const float* W1  = (const float*)d_in[20]; const float* bb1 = (const float*)d_in[21];
  const float* W2  = (const float*)d_in[22]; const float* bb2 = (const float*)d_in[23];

  char* ws = (char*)d_ws;
  const size_t MB = 1024ull * 1024ull;
  short* xb   = (short*)(ws + 0);          // 8MB; reused as attention output
  short* woT  = (short*)(ws + 8 * MB);     // 2MB
  short* w1T  = (short*)(ws + 10 * MB);    // 8MB
  short* w2T  = (short*)(ws + 18 * MB);    // 8MB
  short* wqeB = (short*)(ws + 26 * MB);    // 2MB each (dead after fusion gemm)
  short* wkeB = (short*)(ws + 28 * MB);
  short* wveB = (short*)(ws + 30 * MB);
  short* wqT  = (short*)(ws + 32 * MB);
  short* wkT  = (short*)(ws + 34 * MB);
  short* wvT  = (short*)(ws + 36 * MB);
  short* wcqT = (short*)(ws + 38 * MB);    // fused weights (dead after QKV)
  short* wckT = (short*)(ws + 40 * MB);
  short* wcvT = (short*)(ws + 42 * MB);
  float* bcq  = (float*)(ws + 44 * MB);
  float* bck  = (float*)(ws + 44 * MB + 16384);
  float* bcv  = (float*)(ws + 44 * MB + 32768);
  short* Qb   = (short*)(ws + 45 * MB);    // 8MB (dead after attention)
  short* Kb2  = (short*)(ws + 53 * MB);    // 8MB
  short* VTb  = (short*)(ws + 61 * MB);    // 8MB (dead after attention)
  float* mhaP0= (float*)(ws + 26 * MB);    // 16MB [Wo .. LN1]
  float* mhaP1= (float*)(ws + 42 * MB);    // 16MB
  short* Hb   = (short*)(ws + 26 * MB);    // 32MB [FFN1 .. FFN2]
  float* yf   = (float*)(ws + 58 * MB);    // 16MB
  short* ybf  = (short*)(ws + 74 * MB);    // 8MB (dead after FFN1)
  float* ffnP0= (float*)d_out;             // 16MB [FFN2 .. LN2]
  float* ffnP1= (float*)(ws + 0);          // 16MB (xb/woT/w1T dead by FFN2)
  short* Aout = xb;

  // 1. conversions
  CvtArgs ca = {};
  ca.S[0] = x;  ca.D[0] = xb;   ca.n[0] = (long)TOK * DM;
  ca.S[1] = Wqe; ca.D[1] = wqeB; ca.n[1] = (long)DM * DM;
  ca.S[2] = Wke; ca.D[2] = wkeB; ca.n[2] = (long)DM * DM;
  ca.S[3] = Wve; ca.D[3] = wveB; ca.n[3] = (long)DM * DM;
  cvt_bf16_b<<<dim3((long)TOK * DM / 2048, 4), 256, 0, stream>>>(ca);

  Tcvt6Args t6 = {};
  t6.W[0] = Wq; t6.WT[0] = wqT;  t6.W[1] = Wk; t6.WT[1] = wkT;
  t6.W[2] = Wv; t6.WT[2] = wvT;  t6.W[3] = Wo; t6.WT[3] = woT;
  t6.W[4] = W1; t6.WT[4] = w1T;  t6.W[5] = W2; t6.WT[5] = w2T;
  transpose_cvt6<<<dim3(3072), 256, 0, stream>>>(t6);

  // 2. fused weights: WcT_z = Wz^T @ Wze^T, bf16 (128^2 kernel)
  GemmArgs fa = {};
  fa.A[0] = wqT;  fa.A[1] = wkT;  fa.A[2] = wvT;
  fa.B[0] = wqeB; fa.B[1] = wkeB; fa.B[2] = wveB;
  fa.C[0] = wcqT; fa.C[1] = wckT; fa.C[2] = wcvT;
  fa.oscale[0] = 1.f; fa.oscale[1] = 1.f; fa.oscale[2] = 1.f;
  fa.M = DM; fa.N = DM; fa.K = DM; fa.tmask = 0; fa.zshift = 0;
  gemm_bt<0><<<dim3(8, 8, 3), 256, 0, stream>>>(fa);

  // 3. fused biases
  BiasArgs ba = {};
  ba.be[0] = bqe; ba.be[1] = bke; ba.be[2] = bve;
  ba.WT[0] = wqT; ba.WT[1] = wkT; ba.WT[2] = wvT;
  ba.b2[0] = bq;  ba.b2[1] = bk;  ba.b2[2] = bv;
  ba.bc[0] = bcq; ba.bc[1] = bck; ba.bc[2] = bcv; ba.K = DM;
  fuse_bias<<<dim3(DM, 3), 64, 0, stream>>>(ba);

  // 4. Q,K,V = xb @ Wc + bc (gemm256; V transposed; Q in exp2 domain)
  Gemm256Args qa = {};
  qa.A[0] = xb;   qa.A[1] = xb;   qa.A[2] = xb;
  qa.B[0] = wcqT; qa.B[1] = wckT; qa.B[2] = wcvT;
  qa.bias[0] = bcq; qa.bias[1] = bck; qa.bias[2] = bcv;
  qa.C[0] = Qb; qa.C[1] = Kb2; qa.C[2] = VTb;
  qa.oscale[0] = 0.125f * 1.44269504f; qa.oscale[1] = 1.f; qa.oscale[2] = 1.f;
  qa.M = TOK; qa.N = DM; qa.K = DM; qa.tmask = 4;
  gemm256<0><<<dim3(4, 16, 3), 512, 0, stream>>>(qa);

  // 5. attention (8-wave, QBLK=128, KVBLK=128)
  flash_attn<<<dim3(TSEQ / 128, 2 * NH), 512, 0, stream>>>(Qb, Kb2, VTb, msk, Aout);

  // 6. mha partials = Aout @ Wo (128^2 split-K x2, f32)
  GemmArgs oa = {};
  oa.A[0] = Aout; oa.B[0] = woT; oa.bias[0] = nullptr;
  oa.C[0] = mhaP0; oa.C[1] = mhaP1;
  oa.oscale[0] = 1.f;
  oa.M = TOK; oa.N = DM; oa.K = DM; oa.tmask = 0; oa.zshift = 1;
  gemm_bt<1><<<dim3(8, 32, 2), 256, 0, stream>>>(oa);

  // 7. y = LN(x + mhaP0 + mhaP1 + bo)
  ln_residual<true><<<dim3(TOK), 256, 0, stream>>>(x, mhaP0, mhaP1, bo,
                                                   g1, b1, yf, ybf);

  // 8. H = gelu(y @ W1 + bb1)  (gemm256)
  Gemm256Args f1 = {};
  f1.A[0] = ybf; f1.B[0] = w1T; f1.bias[0] = bb1; f1.C[0] = Hb;
  f1.oscale[0] = 1.f;
  f1.M = TOK; f1.N = DFF; f1.K = DM; f1.tmask = 0;
  gemm256<2><<<dim3(16, 16, 1), 512, 0, stream>>>(f1);

  // 9. ffn partials = H @ W2 (128^2 split-K x2, f32)
  GemmArgs f2 = {};
  f2.A[0] = Hb; f2.B[0] = w2T; f2.bias[0] = nullptr;
  f2.C[0] = ffnP0; f2.C[1] = ffnP1;
  f2.oscale[0] = 1.f;
  f2.M = TOK; f2.N = DM; f2.K = DFF; f2.tmask = 0; f2.zshift = 1;
  gemm_bt<1><<<dim3(8, 32, 2), 256, 0, stream>>>(f2);

  // 10. out = LN(yf + ffnP0 + ffnP1 + bb2)
  ln_residual<false><<<dim3(TOK), 256, 0, stream>>>(yf, ffnP0, ffnP1, bb2,
                                                    g2, b2, (float*)d_out, nullptr);
}